// Round 4
// baseline (1170.440 us; speedup 1.0000x reference)
//
#include <hip/hip_runtime.h>
#include <hip/hip_bf16.h>

// Problem constants (from reference)
#define N_NODES 100000
#define S_EDGE  32
#define M_ADJ   64
#define BATCH   1024
// randint span = ITEM_HI+1 - ITEM_LO = 40000; 2^32 mod 40000 = 7296
#define SPAN    40000u
#define MULT    7296u

// OUTPUT: float* d_out, 4096 floats: [neg(2x1024) | prob(2x1024)] (proved R3).
// RNG (JAX modern, jax_threefry_partitionable=True):
//   randint(key,shape,0,40000): k1,k2 = split(key)  [foldlike: ki = threefry(key,(0,i))]
//   random_bits(k,32,shape)[j] = w0 ^ w1 of threefry(k, (0, j))   (XOR combine)
//   offset = ((hi%span)*((2^32)%span) + lo%span) % span
//   fold_in(key,d) = threefry(key,(0,d))

// ---------------- Threefry-2x32 (exact JAX schedule) ----------------
__host__ __device__ inline void threefry2x32(unsigned k0, unsigned k1,
                                             unsigned x0, unsigned x1,
                                             unsigned* o0, unsigned* o1)
{
  unsigned ks2 = k0 ^ k1 ^ 0x1BD11BDAu;
  unsigned v0 = x0 + k0, v1 = x1 + k1;
#define RL(x,d) (((x) << (d)) | ((x) >> (32 - (d))))
#define G4(a,b,c,dd) \
  v0 += v1; v1 = RL(v1,a);  v1 ^= v0; \
  v0 += v1; v1 = RL(v1,b);  v1 ^= v0; \
  v0 += v1; v1 = RL(v1,c);  v1 ^= v0; \
  v0 += v1; v1 = RL(v1,dd); v1 ^= v0;
  G4(13,15,26,6)  v0 += k1;  v1 += ks2 + 1u;
  G4(17,29,16,24) v0 += ks2; v1 += k0 + 2u;
  G4(13,15,26,6)  v0 += k0;  v1 += k1 + 3u;
  G4(17,29,16,24) v0 += k1;  v1 += ks2 + 4u;
  G4(13,15,26,6)  v0 += ks2; v1 += k0 + 5u;
#undef G4
#undef RL
  *o0 = v0; *o1 = v1;
}

// ---------------- GCN phase ----------------

// y[i,f] = sum_d x[i,d] * W[f,d]    (x: N x 64, W: 32 x 64, y: N x 32)
__global__ __launch_bounds__(256) void k_gemm64x32(
    const float* __restrict__ x, const float* __restrict__ W, float* __restrict__ y)
{
  __shared__ float sw[32 * 65];  // +1 pad: conflict-free stride
  for (int t = threadIdx.x; t < 2048; t += 256) sw[(t >> 6) * 65 + (t & 63)] = W[t];
  __syncthreads();
  int i = blockIdx.x * 8 + (threadIdx.x >> 5);
  int f = threadIdx.x & 31;
  const float* xr = x + (size_t)i * 64;
  const float* wr = sw + f * 65;
  float acc = 0.f;
#pragma unroll
  for (int d = 0; d < 64; ++d) acc += xr[d] * wr[d];
  y[(size_t)i * 32 + f] = acc;
}

// scatter-add 32-wide rows of src (indexed by edge src node e>>5) into acc[dst]
__global__ __launch_bounds__(256) void k_scatter(
    const int* __restrict__ edge, const float* __restrict__ src,
    float* __restrict__ acc, int* __restrict__ cnt)
{
  int e = blockIdx.x * 8 + (threadIdx.x >> 5);   // edge id, grid sized exactly
  int f = threadIdx.x & 31;
  int d = edge[e];                                // dst node
  atomicAdd(acc + (size_t)d * 32 + f, src[(size_t)(e >> 5) * 32 + f]);
  if (cnt != nullptr && f == 0) atomicAdd(cnt + d, 1);
}

// h = leaky( (scatter-mean of x@W1l^T) + b1 + x@W1r^T )   (h overwrites A)
__global__ __launch_bounds__(256) void k_layer1(
    const float* __restrict__ sum1, const int* __restrict__ cnt,
    const float* __restrict__ x, const float* __restrict__ W1r,
    const float* __restrict__ b1, float* __restrict__ h)
{
  __shared__ float sw[32 * 65];
  __shared__ float sb[32];
  for (int t = threadIdx.x; t < 2048; t += 256) sw[(t >> 6) * 65 + (t & 63)] = W1r[t];
  if (threadIdx.x < 32) sb[threadIdx.x] = b1[threadIdx.x];
  __syncthreads();
  int i = blockIdx.x * 8 + (threadIdx.x >> 5);
  int f = threadIdx.x & 31;
  float c = fmaxf((float)cnt[i], 1.f);
  float mean = sum1[(size_t)i * 32 + f] / c;
  const float* xr = x + (size_t)i * 64;
  const float* wr = sw + f * 65;
  float acc = 0.f;
#pragma unroll
  for (int d = 0; d < 64; ++d) acc += xr[d] * wr[d];
  float v = (mean + sb[f]) + acc;
  h[(size_t)i * 32 + f] = (v >= 0.f) ? v : 0.01f * v;
}

// gcn = normalize( mean2@W2l^T + b2 + h@W2r^T ), one wave per node, grid-stride.
// IN-PLACE: reads h from A and sum2 from B, writes gcn feat 0..31 -> A row,
// feat 32..63 -> B row (per-row, same-wave load->store dependency is safe).
__global__ __launch_bounds__(64) void k_layer2(
    float* __restrict__ A, float* __restrict__ B, const int* __restrict__ cnt,
    const float* __restrict__ W2l, const float* __restrict__ W2r,
    const float* __restrict__ b2)
{
  int lane = threadIdx.x;               // lane = output feature o (64)
  float wl[32], wr[32];
#pragma unroll
  for (int f = 0; f < 32; ++f) { wl[f] = W2l[lane * 32 + f]; wr[f] = W2r[lane * 32 + f]; }
  float bb = b2[lane];
  for (int i = blockIdx.x; i < N_NODES; i += gridDim.x) {
    float mv = 0.f, hv = 0.f;
    float c = fmaxf((float)cnt[i], 1.f);
    if (lane < 32) mv = B[(size_t)i * 32 + lane] / c;          // sum2 -> mean
    else           hv = A[(size_t)i * 32 + (lane - 32)];       // h
    float acc = 0.f, acc2 = 0.f;
#pragma unroll
    for (int f = 0; f < 32; ++f) {
      acc  += __shfl(mv, f)      * wl[f];
      acc2 += __shfl(hv, 32 + f) * wr[f];
    }
    float t = (acc + bb) + acc2;
    float s = t * t;
#pragma unroll
    for (int o = 32; o > 0; o >>= 1) s += __shfl_xor(s, o);
    float g = t / fmaxf(sqrtf(s), 1e-12f);
    if (lane < 32) A[(size_t)i * 32 + lane]        = g;  // gcn feat 0..31
    else           B[(size_t)i * 32 + (lane - 32)] = g;  // gcn feat 32..63
  }
}

// ---------------- KG phase: one wave (64 lanes) per user ----------------
// gcn row of node n: feats 0..31 at glo + n*32, feats 32..63 at ghi + n*32.

__device__ inline float kg_score(const float* __restrict__ glo,
                                 const float* __restrict__ ghi,
                                 const float* sp, const float* su, int nb)
{
  const float* rl = glo + (size_t)nb * 32;
  const float* rh = ghi + (size_t)nb * 32;
  float acc = 0.f;
#pragma unroll
  for (int d = 0; d < 32; ++d) {
    float t = sp[d] * rl[d];
    t = (t >= 0.f) ? t : 0.01f * t;
    acc += t * su[d];
  }
#pragma unroll
  for (int d = 0; d < 32; ++d) {
    float t = sp[32 + d] * rh[d];
    t = (t >= 0.f) ? t : 0.01f * t;
    acc += t * su[32 + d];
  }
  return acc;
}

__device__ inline float wave_softmax(float acc)   // returns this lane's softmax value
{
  float m = acc;
#pragma unroll
  for (int o = 32; o > 0; o >>= 1) m = fmaxf(m, __shfl_xor(m, o));
  float e = expf(acc - m);
  float Z = e;
#pragma unroll
  for (int o = 32; o > 0; o >>= 1) Z += __shfl_xor(Z, o);
  return e / Z;
}

__device__ inline void load_row(const float* glo, const float* ghi, int node,
                                int lane, float* smem)
{
  smem[lane] = (lane < 32) ? glo[(size_t)node * 32 + lane]
                           : ghi[(size_t)node * 32 + (lane - 32)];
}

// step==1: argmax -> one_hop node + log prob
__global__ __launch_bounds__(64) void k_kg_argmax(
    const float* __restrict__ glo, const float* __restrict__ ghi,
    const int* __restrict__ users, const int* __restrict__ pvec,
    const int* __restrict__ adj, int* __restrict__ sel_out,
    float* __restrict__ logit_out)
{
  int b = blockIdx.x, lane = threadIdx.x;
  int u = users[b], pb = pvec[b];
  __shared__ float su[64], sp[64];
  load_row(glo, ghi, u,  lane, su);
  load_row(glo, ghi, pb, lane, sp);
  __syncthreads();
  int nb = adj[(size_t)pb * 64 + lane];
  float sm = wave_softmax(kg_score(glo, ghi, sp, su, nb));
  float v = sm; int i = lane;
#pragma unroll
  for (int o = 32; o > 0; o >>= 1) {
    float ov = __shfl_xor(v, o); int oi = __shfl_xor(i, o);
    if (ov > v || (ov == v && oi < i)) { v = ov; i = oi; }
  }
  float smw = __shfl(sm, i);
  int sel = __shfl(nb, i);
  if (lane == 0) { sel_out[b] = sel; logit_out[b] = logf(smw); }
}

// step==2: top-32 (stable desc, lax.top_k semantics) + filter_entity RNG.
// RNG keys: k1=(k1a,k1b), k2=(k2a,k2b) are split(fold_in(key(123), d)).
__global__ __launch_bounds__(64) void k_kg_topk(
    const float* __restrict__ glo, const float* __restrict__ ghi,
    const int* __restrict__ users, const int* __restrict__ pos_src,
    const int* __restrict__ nbr_src, const int* __restrict__ adj,
    unsigned k1a, unsigned k1b, unsigned k2a, unsigned k2b,
    int* __restrict__ cand_out, float* __restrict__ logit_out)
{
  int b = blockIdx.x, lane = threadIdx.x;
  int u = users[b], pidx = pos_src[b], nbr = nbr_src[b];
  __shared__ float su[64], sp[64];
  load_row(glo, ghi, u,    lane, su);
  load_row(glo, ghi, pidx, lane, sp);
  __syncthreads();
  int nb = adj[(size_t)nbr * 64 + lane];
  float sm = wave_softmax(kg_score(glo, ghi, sp, su, nb));
  float work = sm;
  int mysel = 0;
#pragma unroll 1
  for (int it = 0; it < 32; ++it) {
    float v = work; int i = lane;
#pragma unroll
    for (int o = 32; o > 0; o >>= 1) {
      float ov = __shfl_xor(v, o); int oi = __shfl_xor(i, o);
      if (ov > v || (ov == v && oi < i)) { v = ov; i = oi; }
    }
    if (lane == it) mysel = i;
    if (lane == i)  work = -1.0f;   // sm >= 0, safe mask sentinel
  }
  float selsm = __shfl(sm, mysel);
  int   selnb = __shfl(nb, mysel);
  if (lane < 32) {
    int cand = selnb;
    if (logit_out != nullptr) logit_out[b * 32 + lane] = logf(selsm);
    // randint: partitionable random_bits(k, 32, (1024,32))[j] = w0^w1 of
    // threefry(k, (0, j)); offset = ((hi%S)*7296 + lo%S) % S
    unsigned j = (unsigned)(b * 32 + lane);
    unsigned h0, h1, l0, l1;
    threefry2x32(k1a, k1b, 0u, j, &h0, &h1);
    threefry2x32(k2a, k2b, 0u, j, &l0, &l1);
    unsigned hi = h0 ^ h1, lo = l0 ^ l1;
    unsigned rnd = ((hi % SPAN) * MULT + (lo % SPAN)) % SPAN;
    if (cand > 39999 || cand < 0) cand = (int)rnd;
    cand_out[b * 32 + lane] = cand;
  }
}

// prune: argmin ranking -> good_neg, good_logits; writes FLOAT32 outputs + next p
__global__ __launch_bounds__(64) void k_kg_prune(
    const float* __restrict__ disc, const int* __restrict__ users,
    const int* __restrict__ cand, const float* __restrict__ two_log,
    const int* __restrict__ pos2, const float* __restrict__ one_log,
    float* __restrict__ out, int k, int* __restrict__ p_next)
{
  int b = blockIdx.x, lane = threadIdx.x;
  __shared__ float su[64];
  su[lane] = disc[(size_t)users[b] * 64 + lane];
  __syncthreads();
  float r = 1e30f;
  if (lane < 32) {
    const float* dp = disc + (size_t)pos2[b * 32 + lane] * 64;
    const float* dn = disc + (size_t)cand[b * 32 + lane] * 64;
    float acc = 0.f;
#pragma unroll
    for (int d = 0; d < 64; ++d) acc += su[d] * (dp[d] - dn[d]);
    r = acc;
  }
  float v = r; int i = lane;
#pragma unroll
  for (int o = 32; o > 0; o >>= 1) {
    float ov = __shfl_xor(v, o); int oi = __shfl_xor(i, o);
    if (ov < v || (ov == v && oi < i)) { v = ov; i = oi; }
  }
  if (lane == 0) {
    int gn = cand[b * 32 + i];
    float gl = two_log[b * 32 + i] + one_log[b];
    out[k * BATCH + b]             = (float)gn;   // output 0: neg indices
    out[2 * BATCH + k * BATCH + b] = gl;          // output 1: log probs
    p_next[b] = gn;
  }
}

// ---------------- launch ----------------
extern "C" void kernel_launch(void* const* d_in, const int* in_sizes, int n_in,
                              void* d_out, int out_size, void* d_ws, size_t ws_size,
                              hipStream_t stream)
{
  const float* x    = (const float*)d_in[0];
  const float* W1l  = (const float*)d_in[1];
  const float* W1r  = (const float*)d_in[2];
  const float* b1   = (const float*)d_in[3];
  const float* W2l  = (const float*)d_in[4];
  const float* W2r  = (const float*)d_in[5];
  const float* b2   = (const float*)d_in[6];
  const float* disc = (const float*)d_in[7];
  const int*   users= (const int*)d_in[8];
  const int*   pos  = (const int*)d_in[9];
  const int*   adj  = (const int*)d_in[10];
  const int*   edge = (const int*)d_in[11];
  float* out = (float*)d_out;

  // Compact workspace layout (peak ~25.2 MB)
  char* w = (char*)d_ws;
  int*   cnt = (int*)(w);                       // 400,000 B (pad to 409,600)
  float* A   = (float*)(w + 409600);            // 12.8 MB: xW1l -> h -> gcn[0:32]
  float* B   = (float*)(w + 13209600);          // 12.8 MB: sum1 -> sum2 -> gcn[32:64]
  char*  bb  = w + 26009600;                    // small KG buffers (~0.4 MB)
  int*   p_cur       = (int*)(bb);
  int*   one_hop_sel = (int*)(bb + 4096);
  float* one_hop_log = (float*)(bb + 8192);
  int*   cand        = (int*)(bb + 12288);
  float* two_log     = (float*)(bb + 12288 + 131072);
  int*   pos2        = (int*)(bb + 12288 + 262144);

  // --- GCN over all nodes ---
  hipMemsetAsync(cnt, 0, 400000, stream);
  hipMemsetAsync(B, 0, 12800000, stream);
  k_gemm64x32<<<N_NODES / 8, 256, 0, stream>>>(x, W1l, A);
  k_scatter  <<<(N_NODES * S_EDGE) / 8, 256, 0, stream>>>(edge, A, B, cnt);
  k_layer1   <<<N_NODES / 8, 256, 0, stream>>>(B, cnt, x, W1r, b1, A);
  hipMemsetAsync(B, 0, 12800000, stream);
  k_scatter  <<<(N_NODES * S_EDGE) / 8, 256, 0, stream>>>(edge, A, B, nullptr);
  k_layer2   <<<2048, 64, 0, stream>>>(A, B, cnt, W2l, W2r, b2);

  // --- KG walk, K_STEP = 2 ---
  for (int k = 0; k < 2; ++k) {
    // fold_in(key(123), d) = threefry((0,123), (0, d)); split -> foldlike:
    // k1 = threefry(fkey, (0,0)), k2 = threefry(fkey, (0,1))
    unsigned f0, f1, a1a, a1b, a2a, a2b, c1a, c1b, c2a, c2b;
    threefry2x32(0u, 123u, 0u, (unsigned)(2 * k), &f0, &f1);
    threefry2x32(f0, f1, 0u, 0u, &a1a, &a1b);
    threefry2x32(f0, f1, 0u, 1u, &a2a, &a2b);
    threefry2x32(0u, 123u, 0u, (unsigned)(2 * k + 1), &f0, &f1);
    threefry2x32(f0, f1, 0u, 0u, &c1a, &c1b);
    threefry2x32(f0, f1, 0u, 1u, &c2a, &c2b);

    const int* pvec = (k == 0) ? pos : p_cur;
    k_kg_argmax<<<BATCH, 64, 0, stream>>>(A, B, users, pvec, adj, one_hop_sel, one_hop_log);
    k_kg_topk  <<<BATCH, 64, 0, stream>>>(A, B, users, one_hop_sel, one_hop_sel, adj,
                                          a1a, a1b, a2a, a2b, cand, two_log);
    k_kg_topk  <<<BATCH, 64, 0, stream>>>(A, B, users, pvec, users, adj,
                                          c1a, c1b, c2a, c2b, pos2, nullptr);
    k_kg_prune <<<BATCH, 64, 0, stream>>>(disc, users, cand, two_log, pos2,
                                          one_hop_log, out, k, p_cur);
  }
}

// Round 5
// 913.921 us; speedup vs baseline: 1.2807x; 1.2807x over previous
//
#include <hip/hip_runtime.h>
#include <hip/hip_bf16.h>

// Problem constants (from reference)
#define N_NODES 100000
#define N_EDGES (N_NODES * 32)
#define BATCH   1024
#define SPAN    40000u
#define MULT    7296u    // 2^32 mod 40000

// OUTPUT: float* d_out, 4096 floats: [neg(2x1024) | prob(2x1024)] (proved R3).
// R4 profile: 2x k_scatter = 882/1170 us, WRITE_SIZE 500 MB each (102M fp32
// atomics, atomic-throughput bound). Fix: CSR inversion once + gather-agg.

// ---------------- Threefry-2x32 (exact JAX schedule) ----------------
__host__ __device__ inline void threefry2x32(unsigned k0, unsigned k1,
                                             unsigned x0, unsigned x1,
                                             unsigned* o0, unsigned* o1)
{
  unsigned ks2 = k0 ^ k1 ^ 0x1BD11BDAu;
  unsigned v0 = x0 + k0, v1 = x1 + k1;
#define RL(x,d) (((x) << (d)) | ((x) >> (32 - (d))))
#define G4(a,b,c,dd) \
  v0 += v1; v1 = RL(v1,a);  v1 ^= v0; \
  v0 += v1; v1 = RL(v1,b);  v1 ^= v0; \
  v0 += v1; v1 = RL(v1,c);  v1 ^= v0; \
  v0 += v1; v1 = RL(v1,dd); v1 ^= v0;
  G4(13,15,26,6)  v0 += k1;  v1 += ks2 + 1u;
  G4(17,29,16,24) v0 += ks2; v1 += k0 + 2u;
  G4(13,15,26,6)  v0 += k0;  v1 += k1 + 3u;
  G4(17,29,16,24) v0 += k1;  v1 += ks2 + 4u;
  G4(13,15,26,6)  v0 += ks2; v1 += k0 + 5u;
#undef G4
#undef RL
  *o0 = v0; *o1 = v1;
}

// ---------------- CSR build ----------------

__global__ __launch_bounds__(256) void k_count(
    const int* __restrict__ edge, int* __restrict__ deg)
{
  int e = blockIdx.x * 256 + threadIdx.x;
  atomicAdd(deg + edge[e], 1);
}

__global__ __launch_bounds__(256) void k_scan1(
    const int* __restrict__ deg, int* __restrict__ wofs, int* __restrict__ bsum)
{
  __shared__ int s[256];
  int i = blockIdx.x * 256 + threadIdx.x;
  int v = (i < N_NODES) ? deg[i] : 0;
  s[threadIdx.x] = v; __syncthreads();
#pragma unroll
  for (int o = 1; o < 256; o <<= 1) {
    int t = (threadIdx.x >= o) ? s[threadIdx.x - o] : 0;
    __syncthreads(); s[threadIdx.x] += t; __syncthreads();
  }
  if (i < N_NODES) wofs[i] = s[threadIdx.x] - v;   // exclusive
  if (threadIdx.x == 255) bsum[blockIdx.x] = s[255];
}

__global__ __launch_bounds__(512) void k_scan2(int* __restrict__ bsum, int nb)
{
  __shared__ int s[512];
  int v = (threadIdx.x < (unsigned)nb) ? bsum[threadIdx.x] : 0;
  s[threadIdx.x] = v; __syncthreads();
#pragma unroll
  for (int o = 1; o < 512; o <<= 1) {
    int t = (threadIdx.x >= o) ? s[threadIdx.x - o] : 0;
    __syncthreads(); s[threadIdx.x] += t; __syncthreads();
  }
  if (threadIdx.x < (unsigned)nb) bsum[threadIdx.x] = s[threadIdx.x] - v;
}

__global__ __launch_bounds__(256) void k_scan3(
    int* __restrict__ wofs, const int* __restrict__ bsum)
{
  int i = blockIdx.x * 256 + threadIdx.x;
  if (i < N_NODES) wofs[i] += bsum[blockIdx.x];
}

// fill: wofs[d] advances start->end; elist[pos] = src node (= e/32)
__global__ __launch_bounds__(256) void k_fill(
    const int* __restrict__ edge, int* __restrict__ wofs, int* __restrict__ elist)
{
  int e = blockIdx.x * 256 + threadIdx.x;
  int d = edge[e];
  int pos = atomicAdd(wofs + d, 1);
  elist[pos] = e >> 5;
}

// gather-aggregate: out[n][f] = sum over in-edges of src[s][f]; half-wave/node.
// After k_fill, wofs[n] == end == start + deg[n].
__global__ __launch_bounds__(256) void k_gather(
    const int* __restrict__ deg, const int* __restrict__ wofs,
    const int* __restrict__ elist, const float* __restrict__ src,
    float* __restrict__ out)
{
  int node = blockIdx.x * 8 + (threadIdx.x >> 5);
  int f = threadIdx.x & 31;
  int hb = threadIdx.x & 32;            // half-wave base lane for shuffles
  int dg = deg[node];
  int end = wofs[node];
  int start = end - dg;
  float a0 = 0.f, a1 = 0.f, a2 = 0.f, a3 = 0.f;
  for (int base = 0; base < dg; base += 32) {
    int m = dg - base; if (m > 32) m = 32;
    int eid = (base + f < dg) ? elist[start + base + f] : 0;
    int j = 0;
    for (; j + 4 <= m; j += 4) {
      int s0 = __shfl(eid, hb + j);
      int s1 = __shfl(eid, hb + j + 1);
      int s2 = __shfl(eid, hb + j + 2);
      int s3 = __shfl(eid, hb + j + 3);
      a0 += src[(size_t)s0 * 32 + f];
      a1 += src[(size_t)s1 * 32 + f];
      a2 += src[(size_t)s2 * 32 + f];
      a3 += src[(size_t)s3 * 32 + f];
    }
    for (; j < m; ++j) {
      int s0 = __shfl(eid, hb + j);
      a0 += src[(size_t)s0 * 32 + f];
    }
  }
  out[(size_t)node * 32 + f] = (a0 + a1) + (a2 + a3);
}

// ---------------- GCN dense kernels ----------------

__global__ __launch_bounds__(256) void k_gemm64x32(
    const float* __restrict__ x, const float* __restrict__ W, float* __restrict__ y)
{
  __shared__ float sw[32 * 65];
  for (int t = threadIdx.x; t < 2048; t += 256) sw[(t >> 6) * 65 + (t & 63)] = W[t];
  __syncthreads();
  int i = blockIdx.x * 8 + (threadIdx.x >> 5);
  int f = threadIdx.x & 31;
  const float* xr = x + (size_t)i * 64;
  const float* wr = sw + f * 65;
  float acc = 0.f;
#pragma unroll
  for (int d = 0; d < 64; ++d) acc += xr[d] * wr[d];
  y[(size_t)i * 32 + f] = acc;
}

// legacy scatter path (fallback if ws too small for CSR layout)
__global__ __launch_bounds__(256) void k_scatter(
    const int* __restrict__ edge, const float* __restrict__ src,
    float* __restrict__ acc, int* __restrict__ cnt)
{
  int e = blockIdx.x * 8 + (threadIdx.x >> 5);
  int f = threadIdx.x & 31;
  int d = edge[e];
  atomicAdd(acc + (size_t)d * 32 + f, src[(size_t)(e >> 5) * 32 + f]);
  if (cnt != nullptr && f == 0) atomicAdd(cnt + d, 1);
}

__global__ __launch_bounds__(256) void k_layer1(
    const float* __restrict__ sum1, const int* __restrict__ cnt,
    const float* __restrict__ x, const float* __restrict__ W1r,
    const float* __restrict__ b1, float* __restrict__ h)
{
  __shared__ float sw[32 * 65];
  __shared__ float sb[32];
  for (int t = threadIdx.x; t < 2048; t += 256) sw[(t >> 6) * 65 + (t & 63)] = W1r[t];
  if (threadIdx.x < 32) sb[threadIdx.x] = b1[threadIdx.x];
  __syncthreads();
  int i = blockIdx.x * 8 + (threadIdx.x >> 5);
  int f = threadIdx.x & 31;
  float c = fmaxf((float)cnt[i], 1.f);
  float mean = sum1[(size_t)i * 32 + f] / c;
  const float* xr = x + (size_t)i * 64;
  const float* wr = sw + f * 65;
  float acc = 0.f;
#pragma unroll
  for (int d = 0; d < 64; ++d) acc += xr[d] * wr[d];
  float v = (mean + sb[f]) + acc;
  h[(size_t)i * 32 + f] = (v >= 0.f) ? v : 0.01f * v;
}

__global__ __launch_bounds__(64) void k_layer2(
    float* __restrict__ A, float* __restrict__ B, const int* __restrict__ cnt,
    const float* __restrict__ W2l, const float* __restrict__ W2r,
    const float* __restrict__ b2)
{
  int lane = threadIdx.x;
  float wl[32], wr[32];
#pragma unroll
  for (int f = 0; f < 32; ++f) { wl[f] = W2l[lane * 32 + f]; wr[f] = W2r[lane * 32 + f]; }
  float bb = b2[lane];
  for (int i = blockIdx.x; i < N_NODES; i += gridDim.x) {
    float mv = 0.f, hv = 0.f;
    float c = fmaxf((float)cnt[i], 1.f);
    if (lane < 32) mv = B[(size_t)i * 32 + lane] / c;
    else           hv = A[(size_t)i * 32 + (lane - 32)];
    float acc = 0.f, acc2 = 0.f;
#pragma unroll
    for (int f = 0; f < 32; ++f) {
      acc  += __shfl(mv, f)      * wl[f];
      acc2 += __shfl(hv, 32 + f) * wr[f];
    }
    float t = (acc + bb) + acc2;
    float s = t * t;
#pragma unroll
    for (int o = 32; o > 0; o >>= 1) s += __shfl_xor(s, o);
    float g = t / fmaxf(sqrtf(s), 1e-12f);
    if (lane < 32) A[(size_t)i * 32 + lane]        = g;
    else           B[(size_t)i * 32 + (lane - 32)] = g;
  }
}

// ---------------- KG phase ----------------

__device__ inline float kg_score(const float* __restrict__ glo,
                                 const float* __restrict__ ghi,
                                 const float* sp, const float* su, int nb)
{
  const float* rl = glo + (size_t)nb * 32;
  const float* rh = ghi + (size_t)nb * 32;
  float acc = 0.f;
#pragma unroll
  for (int d = 0; d < 32; ++d) {
    float t = sp[d] * rl[d];
    t = (t >= 0.f) ? t : 0.01f * t;
    acc += t * su[d];
  }
#pragma unroll
  for (int d = 0; d < 32; ++d) {
    float t = sp[32 + d] * rh[d];
    t = (t >= 0.f) ? t : 0.01f * t;
    acc += t * su[32 + d];
  }
  return acc;
}

__device__ inline float wave_softmax(float acc)
{
  float m = acc;
#pragma unroll
  for (int o = 32; o > 0; o >>= 1) m = fmaxf(m, __shfl_xor(m, o));
  float e = expf(acc - m);
  float Z = e;
#pragma unroll
  for (int o = 32; o > 0; o >>= 1) Z += __shfl_xor(Z, o);
  return e / Z;
}

__device__ inline void load_row(const float* glo, const float* ghi, int node,
                                int lane, float* smem)
{
  smem[lane] = (lane < 32) ? glo[(size_t)node * 32 + lane]
                           : ghi[(size_t)node * 32 + (lane - 32)];
}

__global__ __launch_bounds__(64) void k_kg_argmax(
    const float* __restrict__ glo, const float* __restrict__ ghi,
    const int* __restrict__ users, const int* __restrict__ pvec,
    const int* __restrict__ adj, int* __restrict__ sel_out,
    float* __restrict__ logit_out)
{
  int b = blockIdx.x, lane = threadIdx.x;
  int u = users[b], pb = pvec[b];
  __shared__ float su[64], sp[64];
  load_row(glo, ghi, u,  lane, su);
  load_row(glo, ghi, pb, lane, sp);
  __syncthreads();
  int nb = adj[(size_t)pb * 64 + lane];
  float sm = wave_softmax(kg_score(glo, ghi, sp, su, nb));
  float v = sm; int i = lane;
#pragma unroll
  for (int o = 32; o > 0; o >>= 1) {
    float ov = __shfl_xor(v, o); int oi = __shfl_xor(i, o);
    if (ov > v || (ov == v && oi < i)) { v = ov; i = oi; }
  }
  float smw = __shfl(sm, i);
  int sel = __shfl(nb, i);
  if (lane == 0) { sel_out[b] = sel; logit_out[b] = logf(smw); }
}

// merged: variant 0 = cand/two_log (nbr=one_hop), variant 1 = pos2 (nbr=users)
__global__ __launch_bounds__(64) void k_kg_topk2(
    const float* __restrict__ glo, const float* __restrict__ ghi,
    const int* __restrict__ users, const int* __restrict__ srcA,
    const int* __restrict__ pvecB, const int* __restrict__ adj,
    unsigned a1a, unsigned a1b, unsigned a2a, unsigned a2b,
    unsigned c1a, unsigned c1b, unsigned c2a, unsigned c2b,
    int* __restrict__ candA, float* __restrict__ logA, int* __restrict__ candB)
{
  int b = blockIdx.x & (BATCH - 1);
  int var = blockIdx.x >> 10;
  int lane = threadIdx.x;
  int u = users[b];
  int pidx = (var == 0) ? srcA[b] : pvecB[b];
  int nbr  = (var == 0) ? srcA[b] : u;
  unsigned k1a = (var == 0) ? a1a : c1a, k1b = (var == 0) ? a1b : c1b;
  unsigned k2a = (var == 0) ? a2a : c2a, k2b = (var == 0) ? a2b : c2b;
  int* cand_out = (var == 0) ? candA : candB;
  float* logit_out = (var == 0) ? logA : nullptr;

  __shared__ float su[64], sp[64];
  load_row(glo, ghi, u,    lane, su);
  load_row(glo, ghi, pidx, lane, sp);
  __syncthreads();
  int nb = adj[(size_t)nbr * 64 + lane];
  float sm = wave_softmax(kg_score(glo, ghi, sp, su, nb));
  float work = sm;
  int mysel = 0;
#pragma unroll 1
  for (int it = 0; it < 32; ++it) {
    float v = work; int i = lane;
#pragma unroll
    for (int o = 32; o > 0; o >>= 1) {
      float ov = __shfl_xor(v, o); int oi = __shfl_xor(i, o);
      if (ov > v || (ov == v && oi < i)) { v = ov; i = oi; }
    }
    if (lane == it) mysel = i;
    if (lane == i)  work = -1.0f;
  }
  float selsm = __shfl(sm, mysel);
  int   selnb = __shfl(nb, mysel);
  if (lane < 32) {
    int cand = selnb;
    if (logit_out != nullptr) logit_out[b * 32 + lane] = logf(selsm);
    unsigned j = (unsigned)(b * 32 + lane);
    unsigned h0, h1, l0, l1;
    threefry2x32(k1a, k1b, 0u, j, &h0, &h1);
    threefry2x32(k2a, k2b, 0u, j, &l0, &l1);
    unsigned hi = h0 ^ h1, lo = l0 ^ l1;
    unsigned rnd = ((hi % SPAN) * MULT + (lo % SPAN)) % SPAN;
    if (cand > 39999 || cand < 0) cand = (int)rnd;
    cand_out[b * 32 + lane] = cand;
  }
}

__global__ __launch_bounds__(64) void k_kg_prune(
    const float* __restrict__ disc, const int* __restrict__ users,
    const int* __restrict__ cand, const float* __restrict__ two_log,
    const int* __restrict__ pos2, const float* __restrict__ one_log,
    float* __restrict__ out, int k, int* __restrict__ p_next)
{
  int b = blockIdx.x, lane = threadIdx.x;
  __shared__ float su[64];
  su[lane] = disc[(size_t)users[b] * 64 + lane];
  __syncthreads();
  float r = 1e30f;
  if (lane < 32) {
    const float* dp = disc + (size_t)pos2[b * 32 + lane] * 64;
    const float* dn = disc + (size_t)cand[b * 32 + lane] * 64;
    float acc = 0.f;
#pragma unroll
    for (int d = 0; d < 64; ++d) acc += su[d] * (dp[d] - dn[d]);
    r = acc;
  }
  float v = r; int i = lane;
#pragma unroll
  for (int o = 32; o > 0; o >>= 1) {
    float ov = __shfl_xor(v, o); int oi = __shfl_xor(i, o);
    if (ov < v || (ov == v && oi < i)) { v = ov; i = oi; }
  }
  if (lane == 0) {
    int gn = cand[b * 32 + i];
    float gl = two_log[b * 32 + i] + one_log[b];
    out[k * BATCH + b]             = (float)gn;
    out[2 * BATCH + k * BATCH + b] = gl;
    p_next[b] = gn;
  }
}

// ---------------- launch ----------------
extern "C" void kernel_launch(void* const* d_in, const int* in_sizes, int n_in,
                              void* d_out, int out_size, void* d_ws, size_t ws_size,
                              hipStream_t stream)
{
  const float* x    = (const float*)d_in[0];
  const float* W1l  = (const float*)d_in[1];
  const float* W1r  = (const float*)d_in[2];
  const float* b1   = (const float*)d_in[3];
  const float* W2l  = (const float*)d_in[4];
  const float* W2r  = (const float*)d_in[5];
  const float* b2   = (const float*)d_in[6];
  const float* disc = (const float*)d_in[7];
  const int*   users= (const int*)d_in[8];
  const int*   pos  = (const int*)d_in[9];
  const int*   adj  = (const int*)d_in[10];
  const int*   edge = (const int*)d_in[11];
  float* out = (float*)d_out;

  char* w = (char*)d_ws;
  // CSR layout (needs ~39.8 MB)
  int*   deg   = (int*)(w);                     //   0.40 MB
  int*   wofs  = (int*)(w + 409600);            //   0.40 MB
  int*   bsum  = (int*)(w + 819200);            //   4 KB (391 ints)
  char*  bb    = w + 823296;                    //   KG small buffers
  int*   p_cur       = (int*)(bb);
  int*   one_hop_sel = (int*)(bb + 4096);
  float* one_hop_log = (float*)(bb + 8192);
  int*   cand        = (int*)(bb + 12288);
  float* two_log     = (float*)(bb + 143360);
  int*   pos2        = (int*)(bb + 274432);
  int*   elist = (int*)(w + 1310720);           //  12.8 MB
  float* A     = (float*)(w + 14110720);        //  12.8 MB: xW1l -> h -> gcn_lo
  float* B     = (float*)(w + 26910720);        //  12.8 MB: sum -> gcn_hi
  const size_t CSR_NEED = 39710720;

  const int SCAN_B = (N_NODES + 255) / 256;     // 391

  if (ws_size >= CSR_NEED) {
    // --- CSR build (once; graph reused for both aggregations) ---
    hipMemsetAsync(deg, 0, 409600, stream);
    k_count<<<N_EDGES / 256, 256, 0, stream>>>(edge, deg);
    k_scan1<<<SCAN_B, 256, 0, stream>>>(deg, wofs, bsum);
    k_scan2<<<1, 512, 0, stream>>>(bsum, SCAN_B);
    k_scan3<<<SCAN_B, 256, 0, stream>>>(wofs, bsum);
    k_gemm64x32<<<N_NODES / 8, 256, 0, stream>>>(x, W1l, A);   // overlaps fill deps
    k_fill<<<N_EDGES / 256, 256, 0, stream>>>(edge, wofs, elist);
    // --- GCN ---
    k_gather<<<N_NODES / 8, 256, 0, stream>>>(deg, wofs, elist, A, B);
    k_layer1<<<N_NODES / 8, 256, 0, stream>>>(B, deg, x, W1r, b1, A);
    k_gather<<<N_NODES / 8, 256, 0, stream>>>(deg, wofs, elist, A, B);
    k_layer2<<<2048, 64, 0, stream>>>(A, B, deg, W2l, W2r, b2);
  } else {
    // fallback: proven atomic-scatter path (R4), ~25.2 MB
    float* Af = (float*)(w + 409600);
    float* Bf = (float*)(w + 13209600);
    hipMemsetAsync(deg, 0, 400000, stream);
    hipMemsetAsync(Bf, 0, 12800000, stream);
    k_gemm64x32<<<N_NODES / 8, 256, 0, stream>>>(x, W1l, Af);
    k_scatter<<<N_EDGES / 8, 256, 0, stream>>>(edge, Af, Bf, deg);
    k_layer1<<<N_NODES / 8, 256, 0, stream>>>(Bf, deg, x, W1r, b1, Af);
    hipMemsetAsync(Bf, 0, 12800000, stream);
    k_scatter<<<N_EDGES / 8, 256, 0, stream>>>(edge, Af, Bf, nullptr);
    k_layer2<<<2048, 64, 0, stream>>>(Af, Bf, deg, W2l, W2r, b2);
    A = Af; B = Bf;
    bb = w + 26009600;
    p_cur       = (int*)(bb);
    one_hop_sel = (int*)(bb + 4096);
    one_hop_log = (float*)(bb + 8192);
    cand        = (int*)(bb + 12288);
    two_log     = (float*)(bb + 143360);
    pos2        = (int*)(bb + 274432);
  }

  // --- KG walk, K_STEP = 2 ---
  for (int k = 0; k < 2; ++k) {
    unsigned f0, f1, a1a, a1b, a2a, a2b, c1a, c1b, c2a, c2b;
    threefry2x32(0u, 123u, 0u, (unsigned)(2 * k), &f0, &f1);
    threefry2x32(f0, f1, 0u, 0u, &a1a, &a1b);
    threefry2x32(f0, f1, 0u, 1u, &a2a, &a2b);
    threefry2x32(0u, 123u, 0u, (unsigned)(2 * k + 1), &f0, &f1);
    threefry2x32(f0, f1, 0u, 0u, &c1a, &c1b);
    threefry2x32(f0, f1, 0u, 1u, &c2a, &c2b);

    const int* pvec = (k == 0) ? pos : p_cur;
    k_kg_argmax<<<BATCH, 64, 0, stream>>>(A, B, users, pvec, adj, one_hop_sel, one_hop_log);
    k_kg_topk2<<<2 * BATCH, 64, 0, stream>>>(A, B, users, one_hop_sel, pvec, adj,
                                             a1a, a1b, a2a, a2b, c1a, c1b, c2a, c2b,
                                             cand, two_log, pos2);
    k_kg_prune<<<BATCH, 64, 0, stream>>>(disc, users, cand, two_log, pos2,
                                         one_hop_log, out, k, p_cur);
  }
}

// Round 7
// 744.999 us; speedup vs baseline: 1.5711x; 1.2267x over previous
//
#include <hip/hip_runtime.h>
#include <hip/hip_bf16.h>

// Problem constants (from reference)
#define N_NODES 100000
#define N_EDGES (N_NODES * 32)
#define BATCH   1024
#define SPAN    40000u
#define MULT    7296u    // 2^32 mod 40000

// OUTPUT: float* d_out, 4096 floats: [neg(2x1024) | prob(2x1024)] (proved R3).
// R4: atomic scatter 2x441us (500 MB atomic write traffic each).
// R5: CSR; k_fill = 315us (random 4B stores dirty one 64B line/edge, 195 MB).
// R6: LL inversion HUNG: degbuf overlapped next[] -> corrupted chains ->
//     cycles -> infinite chase. Fix: degbuf aliases KG small buffers (deg's
//     last read = k_layer2, KG writes start after) — no overlap with next.

// ---------------- Threefry-2x32 (exact JAX schedule) ----------------
__host__ __device__ inline void threefry2x32(unsigned k0, unsigned k1,
                                             unsigned x0, unsigned x1,
                                             unsigned* o0, unsigned* o1)
{
  unsigned ks2 = k0 ^ k1 ^ 0x1BD11BDAu;
  unsigned v0 = x0 + k0, v1 = x1 + k1;
#define RL(x,d) (((x) << (d)) | ((x) >> (32 - (d))))
#define G4(a,b,c,dd) \
  v0 += v1; v1 = RL(v1,a);  v1 ^= v0; \
  v0 += v1; v1 = RL(v1,b);  v1 ^= v0; \
  v0 += v1; v1 = RL(v1,c);  v1 ^= v0; \
  v0 += v1; v1 = RL(v1,dd); v1 ^= v0;
  G4(13,15,26,6)  v0 += k1;  v1 += ks2 + 1u;
  G4(17,29,16,24) v0 += ks2; v1 += k0 + 2u;
  G4(13,15,26,6)  v0 += k0;  v1 += k1 + 3u;
  G4(17,29,16,24) v0 += k1;  v1 += ks2 + 4u;
  G4(13,15,26,6)  v0 += ks2; v1 += k0 + 5u;
#undef G4
#undef RL
  *o0 = v0; *o1 = v1;
}

// ---------------- Linked-list graph inversion ----------------
// Two sublists per node (sub = e & 1): the gather chases 2 chains in parallel
// per half-wave (ILP over dependent-load latency).

__global__ __launch_bounds__(256) void k_fill_ll(
    const int* __restrict__ edge, int* __restrict__ head, int* __restrict__ next)
{
  int e = blockIdx.x * 256 + threadIdx.x;
  int d = edge[e];
  int sub = e & 1;
  int old = atomicExch(head + sub * N_NODES + d, e);
  next[e] = old;                       // coalesced by e
}

// gather-aggregate via linked list; half-wave (32 lanes = features) per node.
// Lanes f=0,1 chase sublists 0,1; edge ids broadcast to the half via shuffle.
// Also counts in-degree (first gather only).
__global__ __launch_bounds__(256) void k_gather_ll(
    const int* __restrict__ head, const int* __restrict__ next,
    const float* __restrict__ src, float* __restrict__ out,
    int* __restrict__ deg_out)
{
  int node = blockIdx.x * 8 + (threadIdx.x >> 5);
  int f = threadIdx.x & 31;
  int hb = threadIdx.x & 32;            // half-base lane within the 64-wide wave
  int e = (f < 2) ? head[f * N_NODES + node] : -1;
  float acc0 = 0.f, acc1 = 0.f;
  int c01 = 0;
  while (true) {
    int e0 = __shfl(e, hb + 0);
    int e1 = __shfl(e, hb + 1);
    if (e0 == -1 && e1 == -1) break;
    int en = -1;
    if (f < 2 && e != -1) en = next[e];      // dependent chase load
    if (e0 != -1) { acc0 += src[(size_t)(e0 >> 5) * 32 + f]; c01++; }
    if (e1 != -1) { acc1 += src[(size_t)(e1 >> 5) * 32 + f]; c01++; }
    e = en;
  }
  out[(size_t)node * 32 + f] = acc0 + acc1;
  if (deg_out != nullptr && f == 0) deg_out[node] = c01;
}

// ---------------- GCN dense kernels ----------------

__global__ __launch_bounds__(256) void k_gemm64x32(
    const float* __restrict__ x, const float* __restrict__ W, float* __restrict__ y)
{
  __shared__ float sw[32 * 65];
  for (int t = threadIdx.x; t < 2048; t += 256) sw[(t >> 6) * 65 + (t & 63)] = W[t];
  __syncthreads();
  int i = blockIdx.x * 8 + (threadIdx.x >> 5);
  int f = threadIdx.x & 31;
  const float* xr = x + (size_t)i * 64;
  const float* wr = sw + f * 65;
  float acc = 0.f;
#pragma unroll
  for (int d = 0; d < 64; ++d) acc += xr[d] * wr[d];
  y[(size_t)i * 32 + f] = acc;
}

// legacy scatter path (fallback if ws too small for LL layout)
__global__ __launch_bounds__(256) void k_scatter(
    const int* __restrict__ edge, const float* __restrict__ src,
    float* __restrict__ acc, int* __restrict__ cnt)
{
  int e = blockIdx.x * 8 + (threadIdx.x >> 5);
  int f = threadIdx.x & 31;
  int d = edge[e];
  atomicAdd(acc + (size_t)d * 32 + f, src[(size_t)(e >> 5) * 32 + f]);
  if (cnt != nullptr && f == 0) atomicAdd(cnt + d, 1);
}

__global__ __launch_bounds__(256) void k_layer1(
    const float* __restrict__ sum1, const int* __restrict__ cnt,
    const float* __restrict__ x, const float* __restrict__ W1r,
    const float* __restrict__ b1, float* __restrict__ h)
{
  __shared__ float sw[32 * 65];
  __shared__ float sb[32];
  for (int t = threadIdx.x; t < 2048; t += 256) sw[(t >> 6) * 65 + (t & 63)] = W1r[t];
  if (threadIdx.x < 32) sb[threadIdx.x] = b1[threadIdx.x];
  __syncthreads();
  int i = blockIdx.x * 8 + (threadIdx.x >> 5);
  int f = threadIdx.x & 31;
  float c = fmaxf((float)cnt[i], 1.f);
  float mean = sum1[(size_t)i * 32 + f] / c;
  const float* xr = x + (size_t)i * 64;
  const float* wr = sw + f * 65;
  float acc = 0.f;
#pragma unroll
  for (int d = 0; d < 64; ++d) acc += xr[d] * wr[d];
  float v = (mean + sb[f]) + acc;
  h[(size_t)i * 32 + f] = (v >= 0.f) ? v : 0.01f * v;
}

__global__ __launch_bounds__(64) void k_layer2(
    float* __restrict__ A, float* __restrict__ B, const int* __restrict__ cnt,
    const float* __restrict__ W2l, const float* __restrict__ W2r,
    const float* __restrict__ b2)
{
  int lane = threadIdx.x;
  float wl[32], wr[32];
#pragma unroll
  for (int f = 0; f < 32; ++f) { wl[f] = W2l[lane * 32 + f]; wr[f] = W2r[lane * 32 + f]; }
  float bb = b2[lane];
  for (int i = blockIdx.x; i < N_NODES; i += gridDim.x) {
    float mv = 0.f, hv = 0.f;
    float c = fmaxf((float)cnt[i], 1.f);
    if (lane < 32) mv = B[(size_t)i * 32 + lane] / c;
    else           hv = A[(size_t)i * 32 + (lane - 32)];
    float acc = 0.f, acc2 = 0.f;
#pragma unroll
    for (int f = 0; f < 32; ++f) {
      acc  += __shfl(mv, f)      * wl[f];
      acc2 += __shfl(hv, 32 + f) * wr[f];
    }
    float t = (acc + bb) + acc2;
    float s = t * t;
#pragma unroll
    for (int o = 32; o > 0; o >>= 1) s += __shfl_xor(s, o);
    float g = t / fmaxf(sqrtf(s), 1e-12f);
    if (lane < 32) A[(size_t)i * 32 + lane]        = g;
    else           B[(size_t)i * 32 + (lane - 32)] = g;
  }
}

// ---------------- KG phase ----------------

__device__ inline float kg_score(const float* __restrict__ glo,
                                 const float* __restrict__ ghi,
                                 const float* sp, const float* su, int nb)
{
  const float* rl = glo + (size_t)nb * 32;
  const float* rh = ghi + (size_t)nb * 32;
  float acc = 0.f;
#pragma unroll
  for (int d = 0; d < 32; ++d) {
    float t = sp[d] * rl[d];
    t = (t >= 0.f) ? t : 0.01f * t;
    acc += t * su[d];
  }
#pragma unroll
  for (int d = 0; d < 32; ++d) {
    float t = sp[32 + d] * rh[d];
    t = (t >= 0.f) ? t : 0.01f * t;
    acc += t * su[32 + d];
  }
  return acc;
}

__device__ inline float wave_softmax(float acc)
{
  float m = acc;
#pragma unroll
  for (int o = 32; o > 0; o >>= 1) m = fmaxf(m, __shfl_xor(m, o));
  float e = expf(acc - m);
  float Z = e;
#pragma unroll
  for (int o = 32; o > 0; o >>= 1) Z += __shfl_xor(Z, o);
  return e / Z;
}

__device__ inline void load_row(const float* glo, const float* ghi, int node,
                                int lane, float* smem)
{
  smem[lane] = (lane < 32) ? glo[(size_t)node * 32 + lane]
                           : ghi[(size_t)node * 32 + (lane - 32)];
}

__global__ __launch_bounds__(64) void k_kg_argmax(
    const float* __restrict__ glo, const float* __restrict__ ghi,
    const int* __restrict__ users, const int* __restrict__ pvec,
    const int* __restrict__ adj, int* __restrict__ sel_out,
    float* __restrict__ logit_out)
{
  int b = blockIdx.x, lane = threadIdx.x;
  int u = users[b], pb = pvec[b];
  __shared__ float su[64], sp[64];
  load_row(glo, ghi, u,  lane, su);
  load_row(glo, ghi, pb, lane, sp);
  __syncthreads();
  int nb = adj[(size_t)pb * 64 + lane];
  float sm = wave_softmax(kg_score(glo, ghi, sp, su, nb));
  float v = sm; int i = lane;
#pragma unroll
  for (int o = 32; o > 0; o >>= 1) {
    float ov = __shfl_xor(v, o); int oi = __shfl_xor(i, o);
    if (ov > v || (ov == v && oi < i)) { v = ov; i = oi; }
  }
  float smw = __shfl(sm, i);
  int sel = __shfl(nb, i);
  if (lane == 0) { sel_out[b] = sel; logit_out[b] = logf(smw); }
}

// merged: variant 0 = cand/two_log (nbr=one_hop), variant 1 = pos2 (nbr=users)
__global__ __launch_bounds__(64) void k_kg_topk2(
    const float* __restrict__ glo, const float* __restrict__ ghi,
    const int* __restrict__ users, const int* __restrict__ srcA,
    const int* __restrict__ pvecB, const int* __restrict__ adj,
    unsigned a1a, unsigned a1b, unsigned a2a, unsigned a2b,
    unsigned c1a, unsigned c1b, unsigned c2a, unsigned c2b,
    int* __restrict__ candA, float* __restrict__ logA, int* __restrict__ candB)
{
  int b = blockIdx.x & (BATCH - 1);
  int var = blockIdx.x >> 10;
  int lane = threadIdx.x;
  int u = users[b];
  int pidx = (var == 0) ? srcA[b] : pvecB[b];
  int nbr  = (var == 0) ? srcA[b] : u;
  unsigned k1a = (var == 0) ? a1a : c1a, k1b = (var == 0) ? a1b : c1b;
  unsigned k2a = (var == 0) ? a2a : c2a, k2b = (var == 0) ? a2b : c2b;
  int* cand_out = (var == 0) ? candA : candB;
  float* logit_out = (var == 0) ? logA : nullptr;

  __shared__ float su[64], sp[64];
  load_row(glo, ghi, u,    lane, su);
  load_row(glo, ghi, pidx, lane, sp);
  __syncthreads();
  int nb = adj[(size_t)nbr * 64 + lane];
  float sm = wave_softmax(kg_score(glo, ghi, sp, su, nb));
  float work = sm;
  int mysel = 0;
#pragma unroll 1
  for (int it = 0; it < 32; ++it) {
    float v = work; int i = lane;
#pragma unroll
    for (int o = 32; o > 0; o >>= 1) {
      float ov = __shfl_xor(v, o); int oi = __shfl_xor(i, o);
      if (ov > v || (ov == v && oi < i)) { v = ov; i = oi; }
    }
    if (lane == it) mysel = i;
    if (lane == i)  work = -1.0f;
  }
  float selsm = __shfl(sm, mysel);
  int   selnb = __shfl(nb, mysel);
  if (lane < 32) {
    int cand = selnb;
    if (logit_out != nullptr) logit_out[b * 32 + lane] = logf(selsm);
    unsigned j = (unsigned)(b * 32 + lane);
    unsigned h0, h1, l0, l1;
    threefry2x32(k1a, k1b, 0u, j, &h0, &h1);
    threefry2x32(k2a, k2b, 0u, j, &l0, &l1);
    unsigned hi = h0 ^ h1, lo = l0 ^ l1;
    unsigned rnd = ((hi % SPAN) * MULT + (lo % SPAN)) % SPAN;
    if (cand > 39999 || cand < 0) cand = (int)rnd;
    cand_out[b * 32 + lane] = cand;
  }
}

__global__ __launch_bounds__(64) void k_kg_prune(
    const float* __restrict__ disc, const int* __restrict__ users,
    const int* __restrict__ cand, const float* __restrict__ two_log,
    const int* __restrict__ pos2, const float* __restrict__ one_log,
    float* __restrict__ out, int k, int* __restrict__ p_next)
{
  int b = blockIdx.x, lane = threadIdx.x;
  __shared__ float su[64];
  su[lane] = disc[(size_t)users[b] * 64 + lane];
  __syncthreads();
  float r = 1e30f;
  if (lane < 32) {
    const float* dp = disc + (size_t)pos2[b * 32 + lane] * 64;
    const float* dn = disc + (size_t)cand[b * 32 + lane] * 64;
    float acc = 0.f;
#pragma unroll
    for (int d = 0; d < 64; ++d) acc += su[d] * (dp[d] - dn[d]);
    r = acc;
  }
  float v = r; int i = lane;
#pragma unroll
  for (int o = 32; o > 0; o >>= 1) {
    float ov = __shfl_xor(v, o); int oi = __shfl_xor(i, o);
    if (ov < v || (ov == v && oi < i)) { v = ov; i = oi; }
  }
  if (lane == 0) {
    int gn = cand[b * 32 + i];
    float gl = two_log[b * 32 + i] + one_log[b];
    out[k * BATCH + b]             = (float)gn;
    out[2 * BATCH + k * BATCH + b] = gl;
    p_next[b] = gn;
  }
}

// ---------------- launch ----------------
extern "C" void kernel_launch(void* const* d_in, const int* in_sizes, int n_in,
                              void* d_out, int out_size, void* d_ws, size_t ws_size,
                              hipStream_t stream)
{
  const float* x    = (const float*)d_in[0];
  const float* W1l  = (const float*)d_in[1];
  const float* W1r  = (const float*)d_in[2];
  const float* b1   = (const float*)d_in[3];
  const float* W2l  = (const float*)d_in[4];
  const float* W2r  = (const float*)d_in[5];
  const float* b2   = (const float*)d_in[6];
  const float* disc = (const float*)d_in[7];
  const int*   users= (const int*)d_in[8];
  const int*   pos  = (const int*)d_in[9];
  const int*   adj  = (const int*)d_in[10];
  const int*   edge = (const int*)d_in[11];
  float* out = (float*)d_out;

  char* w = (char*)d_ws;
  // LL layout — 39,710,720 B total (same footprint R5 proved available).
  // [0,        800,000)  head (2 sublists x 100k)
  // [800,000, 1,205,504) KG small buffers; degbuf ALIASES this region
  //                      (deg: written gather-1, last read k_layer2;
  //                       KG buffers first written after k_layer2 — safe,
  //                       and ends 1,205,504 < next @ 1,310,720: NO overlap)
  // [1,310,720, 14,110,720)  next (12.8 MB)
  // [14,110,720, 26,910,720) A
  // [26,910,720, 39,710,720) B
  int*   head  = (int*)(w);
  char*  bb    = w + 800000;
  int*   degbuf      = (int*)(bb);              // aliases KG buffers (see above)
  int*   p_cur       = (int*)(bb);
  int*   one_hop_sel = (int*)(bb + 4096);
  float* one_hop_log = (float*)(bb + 8192);
  int*   cand        = (int*)(bb + 12288);
  float* two_log     = (float*)(bb + 143360);
  int*   pos2        = (int*)(bb + 274432);
  int*   next  = (int*)(w + 1310720);
  float* A     = (float*)(w + 14110720);
  float* B     = (float*)(w + 26910720);
  const size_t LL_NEED = 39710720;

  if (ws_size >= LL_NEED) {
    // --- build inverted index (linked lists), once for both aggregations ---
    hipMemsetAsync(head, 0xFF, 800000, stream);          // heads = -1
    k_fill_ll<<<N_EDGES / 256, 256, 0, stream>>>(edge, head, next);
    k_gemm64x32<<<N_NODES / 8, 256, 0, stream>>>(x, W1l, A);
    // --- GCN ---
    k_gather_ll<<<N_NODES / 8, 256, 0, stream>>>(head, next, A, B, degbuf);
    k_layer1<<<N_NODES / 8, 256, 0, stream>>>(B, degbuf, x, W1r, b1, A);
    k_gather_ll<<<N_NODES / 8, 256, 0, stream>>>(head, next, A, B, nullptr);
    k_layer2<<<2048, 64, 0, stream>>>(A, B, degbuf, W2l, W2r, b2);
  } else {
    // fallback: proven atomic-scatter path (R4), ~25.2 MB
    float* Af = (float*)(w + 409600);
    float* Bf = (float*)(w + 13209600);
    int* cnt = (int*)w;
    hipMemsetAsync(cnt, 0, 400000, stream);
    hipMemsetAsync(Bf, 0, 12800000, stream);
    k_gemm64x32<<<N_NODES / 8, 256, 0, stream>>>(x, W1l, Af);
    k_scatter<<<N_EDGES / 8, 256, 0, stream>>>(edge, Af, Bf, cnt);
    k_layer1<<<N_NODES / 8, 256, 0, stream>>>(Bf, cnt, x, W1r, b1, Af);
    hipMemsetAsync(Bf, 0, 12800000, stream);
    k_scatter<<<N_EDGES / 8, 256, 0, stream>>>(edge, Af, Bf, nullptr);
    k_layer2<<<2048, 64, 0, stream>>>(Af, Bf, cnt, W2l, W2r, b2);
    A = Af; B = Bf;
    bb = w + 26009600;
    p_cur       = (int*)(bb);
    one_hop_sel = (int*)(bb + 4096);
    one_hop_log = (float*)(bb + 8192);
    cand        = (int*)(bb + 12288);
    two_log     = (float*)(bb + 143360);
    pos2        = (int*)(bb + 274432);
  }

  // --- KG walk, K_STEP = 2 ---
  for (int k = 0; k < 2; ++k) {
    unsigned f0, f1, a1a, a1b, a2a, a2b, c1a, c1b, c2a, c2b;
    threefry2x32(0u, 123u, 0u, (unsigned)(2 * k), &f0, &f1);
    threefry2x32(f0, f1, 0u, 0u, &a1a, &a1b);
    threefry2x32(f0, f1, 0u, 1u, &a2a, &a2b);
    threefry2x32(0u, 123u, 0u, (unsigned)(2 * k + 1), &f0, &f1);
    threefry2x32(f0, f1, 0u, 0u, &c1a, &c1b);
    threefry2x32(f0, f1, 0u, 1u, &c2a, &c2b);

    const int* pvec = (k == 0) ? pos : p_cur;
    k_kg_argmax<<<BATCH, 64, 0, stream>>>(A, B, users, pvec, adj, one_hop_sel, one_hop_log);
    k_kg_topk2<<<2 * BATCH, 64, 0, stream>>>(A, B, users, one_hop_sel, pvec, adj,
                                             a1a, a1b, a2a, a2b, c1a, c1b, c2a, c2b,
                                             cand, two_log, pos2);
    k_kg_prune<<<BATCH, 64, 0, stream>>>(disc, users, cand, two_log, pos2,
                                         one_hop_log, out, k, p_cur);
  }
}

// Round 10
// 743.766 us; speedup vs baseline: 1.5737x; 1.0017x over previous
//
#include <hip/hip_runtime.h>
#include <hip/hip_bf16.h>

// Problem constants (from reference)
#define N_NODES 100000
#define N_EDGES (N_NODES * 32)
#define BATCH   1024
#define SPAN    40000u
#define MULT    7296u    // 2^32 mod 40000
#define FILL_B  (N_EDGES / 256)   // 12500 blocks for fill
#define GEMM_B  (N_NODES / 8)     // 12500 blocks for gemm

// History: R4 scatter (882us agg) -> R5 CSR (fill 315us) -> R7 LL-2 745us
// (PASSED) -> R8/R9 fused-KG kernel: IDENTICAL wrong absmax across two
// different barrier structures => deterministic bug in the new fused KG code
// (or NEED8 GCN). R10 = bisection: KG phase reverted to R7-proven 3-dispatch
// kernels VERBATIM; GCN keeps R8's fill+gemm fusion and 8-sublist LL.

// ---------------- Threefry-2x32 (exact JAX schedule) ----------------
__host__ __device__ inline void threefry2x32(unsigned k0, unsigned k1,
                                             unsigned x0, unsigned x1,
                                             unsigned* o0, unsigned* o1)
{
  unsigned ks2 = k0 ^ k1 ^ 0x1BD11BDAu;
  unsigned v0 = x0 + k0, v1 = x1 + k1;
#define RL(x,d) (((x) << (d)) | ((x) >> (32 - (d))))
#define G4(a,b,c,dd) \
  v0 += v1; v1 = RL(v1,a);  v1 ^= v0; \
  v0 += v1; v1 = RL(v1,b);  v1 ^= v0; \
  v0 += v1; v1 = RL(v1,c);  v1 ^= v0; \
  v0 += v1; v1 = RL(v1,dd); v1 ^= v0;
  G4(13,15,26,6)  v0 += k1;  v1 += ks2 + 1u;
  G4(17,29,16,24) v0 += ks2; v1 += k0 + 2u;
  G4(13,15,26,6)  v0 += k0;  v1 += k1 + 3u;
  G4(17,29,16,24) v0 += k1;  v1 += ks2 + 4u;
  G4(13,15,26,6)  v0 += ks2; v1 += k0 + 5u;
#undef G4
#undef RL
  *o0 = v0; *o1 = v1;
}

// ---------------- fused LL-fill + gemm (independent block ranges) ----------
__global__ __launch_bounds__(256) void k_fill_gemm(
    const int* __restrict__ edge, int* __restrict__ head, int* __restrict__ next,
    int nsub, const float* __restrict__ x, const float* __restrict__ W,
    float* __restrict__ y)
{
  __shared__ float sw[32 * 65];
  if (blockIdx.x < FILL_B) {
    int e = blockIdx.x * 256 + threadIdx.x;
    int d = edge[e];
    int sub = e & (nsub - 1);
    int old = atomicExch(head + sub * N_NODES + d, e);
    next[e] = old;                       // coalesced by e
  } else {
    for (int t = threadIdx.x; t < 2048; t += 256) sw[(t >> 6) * 65 + (t & 63)] = W[t];
    __syncthreads();
    int i = (blockIdx.x - FILL_B) * 8 + (threadIdx.x >> 5);
    int f = threadIdx.x & 31;
    const float* xr = x + (size_t)i * 64;
    const float* wr = sw + f * 65;
    float acc = 0.f;
#pragma unroll
    for (int d = 0; d < 64; ++d) acc += xr[d] * wr[d];
    y[(size_t)i * 32 + f] = acc;
  }
}

// gather-aggregate via NSUB linked lists; half-wave (32 lanes) per node.
template<int NSUB>
__global__ __launch_bounds__(256) void k_gather_ll(
    const int* __restrict__ head, const int* __restrict__ next,
    const float* __restrict__ src, float* __restrict__ out,
    int* __restrict__ deg_out)
{
  int node = blockIdx.x * 8 + (threadIdx.x >> 5);
  int f = threadIdx.x & 31;
  int hb = threadIdx.x & 32;
  int e = (f < NSUB) ? head[f * N_NODES + node] : -1;
  float acc = 0.f;
  int cnt = 0;
  while (true) {
    int es[NSUB];
    bool any = false;
#pragma unroll
    for (int j = 0; j < NSUB; ++j) { es[j] = __shfl(e, hb + j); any |= (es[j] != -1); }
    if (!any) break;
    int en = -1;
    if (f < NSUB && e != -1) en = next[e];   // dependent chase load
#pragma unroll
    for (int j = 0; j < NSUB; ++j)
      if (es[j] != -1) { acc += src[(size_t)(es[j] >> 5) * 32 + f]; cnt++; }
    e = en;
  }
  out[(size_t)node * 32 + f] = acc;
  if (deg_out != nullptr && f == 0) deg_out[node] = cnt;
}

// ---------------- GCN dense kernels ----------------

__global__ __launch_bounds__(256) void k_gemm64x32(
    const float* __restrict__ x, const float* __restrict__ W, float* __restrict__ y)
{
  __shared__ float sw[32 * 65];
  for (int t = threadIdx.x; t < 2048; t += 256) sw[(t >> 6) * 65 + (t & 63)] = W[t];
  __syncthreads();
  int i = blockIdx.x * 8 + (threadIdx.x >> 5);
  int f = threadIdx.x & 31;
  const float* xr = x + (size_t)i * 64;
  const float* wr = sw + f * 65;
  float acc = 0.f;
#pragma unroll
  for (int d = 0; d < 64; ++d) acc += xr[d] * wr[d];
  y[(size_t)i * 32 + f] = acc;
}

__global__ __launch_bounds__(256) void k_scatter(
    const int* __restrict__ edge, const float* __restrict__ src,
    float* __restrict__ acc, int* __restrict__ cnt)
{
  int e = blockIdx.x * 8 + (threadIdx.x >> 5);
  int f = threadIdx.x & 31;
  int d = edge[e];
  atomicAdd(acc + (size_t)d * 32 + f, src[(size_t)(e >> 5) * 32 + f]);
  if (cnt != nullptr && f == 0) atomicAdd(cnt + d, 1);
}

__global__ __launch_bounds__(256) void k_layer1(
    const float* __restrict__ sum1, const int* __restrict__ cnt,
    const float* __restrict__ x, const float* __restrict__ W1r,
    const float* __restrict__ b1, float* __restrict__ h)
{
  __shared__ float sw[32 * 65];
  __shared__ float sb[32];
  for (int t = threadIdx.x; t < 2048; t += 256) sw[(t >> 6) * 65 + (t & 63)] = W1r[t];
  if (threadIdx.x < 32) sb[threadIdx.x] = b1[threadIdx.x];
  __syncthreads();
  int i = blockIdx.x * 8 + (threadIdx.x >> 5);
  int f = threadIdx.x & 31;
  float c = fmaxf((float)cnt[i], 1.f);
  float mean = sum1[(size_t)i * 32 + f] / c;
  const float* xr = x + (size_t)i * 64;
  const float* wr = sw + f * 65;
  float acc = 0.f;
#pragma unroll
  for (int d = 0; d < 64; ++d) acc += xr[d] * wr[d];
  float v = (mean + sb[f]) + acc;
  h[(size_t)i * 32 + f] = (v >= 0.f) ? v : 0.01f * v;
}

__global__ __launch_bounds__(64) void k_layer2(
    float* __restrict__ A, float* __restrict__ B, const int* __restrict__ cnt,
    const float* __restrict__ W2l, const float* __restrict__ W2r,
    const float* __restrict__ b2)
{
  int lane = threadIdx.x;
  float wl[32], wr[32];
#pragma unroll
  for (int f = 0; f < 32; ++f) { wl[f] = W2l[lane * 32 + f]; wr[f] = W2r[lane * 32 + f]; }
  float bb = b2[lane];
  for (int i = blockIdx.x; i < N_NODES; i += gridDim.x) {
    float mv = 0.f, hv = 0.f;
    float c = fmaxf((float)cnt[i], 1.f);
    if (lane < 32) mv = B[(size_t)i * 32 + lane] / c;
    else           hv = A[(size_t)i * 32 + (lane - 32)];
    float acc = 0.f, acc2 = 0.f;
#pragma unroll
    for (int f = 0; f < 32; ++f) {
      acc  += __shfl(mv, f)      * wl[f];
      acc2 += __shfl(hv, 32 + f) * wr[f];
    }
    float t = (acc + bb) + acc2;
    float s = t * t;
#pragma unroll
    for (int o = 32; o > 0; o >>= 1) s += __shfl_xor(s, o);
    float g = t / fmaxf(sqrtf(s), 1e-12f);
    if (lane < 32) A[(size_t)i * 32 + lane]        = g;
    else           B[(size_t)i * 32 + (lane - 32)] = g;
  }
}

// ---------------- KG phase: R7-PROVEN kernels, verbatim ----------------

__device__ inline float kg_score(const float* __restrict__ glo,
                                 const float* __restrict__ ghi,
                                 const float* sp, const float* su, int nb)
{
  const float* rl = glo + (size_t)nb * 32;
  const float* rh = ghi + (size_t)nb * 32;
  float acc = 0.f;
#pragma unroll
  for (int d = 0; d < 32; ++d) {
    float t = sp[d] * rl[d];
    t = (t >= 0.f) ? t : 0.01f * t;
    acc += t * su[d];
  }
#pragma unroll
  for (int d = 0; d < 32; ++d) {
    float t = sp[32 + d] * rh[d];
    t = (t >= 0.f) ? t : 0.01f * t;
    acc += t * su[32 + d];
  }
  return acc;
}

__device__ inline float wave_softmax(float acc)
{
  float m = acc;
#pragma unroll
  for (int o = 32; o > 0; o >>= 1) m = fmaxf(m, __shfl_xor(m, o));
  float e = expf(acc - m);
  float Z = e;
#pragma unroll
  for (int o = 32; o > 0; o >>= 1) Z += __shfl_xor(Z, o);
  return e / Z;
}

__device__ inline void load_row(const float* glo, const float* ghi, int node,
                                int lane, float* smem)
{
  smem[lane] = (lane < 32) ? glo[(size_t)node * 32 + lane]
                           : ghi[(size_t)node * 32 + (lane - 32)];
}

__global__ __launch_bounds__(64) void k_kg_argmax(
    const float* __restrict__ glo, const float* __restrict__ ghi,
    const int* __restrict__ users, const int* __restrict__ pvec,
    const int* __restrict__ adj, int* __restrict__ sel_out,
    float* __restrict__ logit_out)
{
  int b = blockIdx.x, lane = threadIdx.x;
  int u = users[b], pb = pvec[b];
  __shared__ float su[64], sp[64];
  load_row(glo, ghi, u,  lane, su);
  load_row(glo, ghi, pb, lane, sp);
  __syncthreads();
  int nb = adj[(size_t)pb * 64 + lane];
  float sm = wave_softmax(kg_score(glo, ghi, sp, su, nb));
  float v = sm; int i = lane;
#pragma unroll
  for (int o = 32; o > 0; o >>= 1) {
    float ov = __shfl_xor(v, o); int oi = __shfl_xor(i, o);
    if (ov > v || (ov == v && oi < i)) { v = ov; i = oi; }
  }
  float smw = __shfl(sm, i);
  int sel = __shfl(nb, i);
  if (lane == 0) { sel_out[b] = sel; logit_out[b] = logf(smw); }
}

// merged: variant 0 = cand/two_log (nbr=one_hop), variant 1 = pos2 (nbr=users)
__global__ __launch_bounds__(64) void k_kg_topk2(
    const float* __restrict__ glo, const float* __restrict__ ghi,
    const int* __restrict__ users, const int* __restrict__ srcA,
    const int* __restrict__ pvecB, const int* __restrict__ adj,
    unsigned a1a, unsigned a1b, unsigned a2a, unsigned a2b,
    unsigned c1a, unsigned c1b, unsigned c2a, unsigned c2b,
    int* __restrict__ candA, float* __restrict__ logA, int* __restrict__ candB)
{
  int b = blockIdx.x & (BATCH - 1);
  int var = blockIdx.x >> 10;
  int lane = threadIdx.x;
  int u = users[b];
  int pidx = (var == 0) ? srcA[b] : pvecB[b];
  int nbr  = (var == 0) ? srcA[b] : u;
  unsigned k1a = (var == 0) ? a1a : c1a, k1b = (var == 0) ? a1b : c1b;
  unsigned k2a = (var == 0) ? a2a : c2a, k2b = (var == 0) ? a2b : c2b;
  int* cand_out = (var == 0) ? candA : candB;
  float* logit_out = (var == 0) ? logA : nullptr;

  __shared__ float su[64], sp[64];
  load_row(glo, ghi, u,    lane, su);
  load_row(glo, ghi, pidx, lane, sp);
  __syncthreads();
  int nb = adj[(size_t)nbr * 64 + lane];
  float sm = wave_softmax(kg_score(glo, ghi, sp, su, nb));
  float work = sm;
  int mysel = 0;
#pragma unroll 1
  for (int it = 0; it < 32; ++it) {
    float v = work; int i = lane;
#pragma unroll
    for (int o = 32; o > 0; o >>= 1) {
      float ov = __shfl_xor(v, o); int oi = __shfl_xor(i, o);
      if (ov > v || (ov == v && oi < i)) { v = ov; i = oi; }
    }
    if (lane == it) mysel = i;
    if (lane == i)  work = -1.0f;
  }
  float selsm = __shfl(sm, mysel);
  int   selnb = __shfl(nb, mysel);
  if (lane < 32) {
    int cand = selnb;
    if (logit_out != nullptr) logit_out[b * 32 + lane] = logf(selsm);
    unsigned j = (unsigned)(b * 32 + lane);
    unsigned h0, h1, l0, l1;
    threefry2x32(k1a, k1b, 0u, j, &h0, &h1);
    threefry2x32(k2a, k2b, 0u, j, &l0, &l1);
    unsigned hi = h0 ^ h1, lo = l0 ^ l1;
    unsigned rnd = ((hi % SPAN) * MULT + (lo % SPAN)) % SPAN;
    if (cand > 39999 || cand < 0) cand = (int)rnd;
    cand_out[b * 32 + lane] = cand;
  }
}

__global__ __launch_bounds__(64) void k_kg_prune(
    const float* __restrict__ disc, const int* __restrict__ users,
    const int* __restrict__ cand, const float* __restrict__ two_log,
    const int* __restrict__ pos2, const float* __restrict__ one_log,
    float* __restrict__ out, int k, int* __restrict__ p_next)
{
  int b = blockIdx.x, lane = threadIdx.x;
  __shared__ float su[64];
  su[lane] = disc[(size_t)users[b] * 64 + lane];
  __syncthreads();
  float r = 1e30f;
  if (lane < 32) {
    const float* dp = disc + (size_t)pos2[b * 32 + lane] * 64;
    const float* dn = disc + (size_t)cand[b * 32 + lane] * 64;
    float acc = 0.f;
#pragma unroll
    for (int d = 0; d < 64; ++d) acc += su[d] * (dp[d] - dn[d]);
    r = acc;
  }
  float v = r; int i = lane;
#pragma unroll
  for (int o = 32; o > 0; o >>= 1) {
    float ov = __shfl_xor(v, o); int oi = __shfl_xor(i, o);
    if (ov < v || (ov == v && oi < i)) { v = ov; i = oi; }
  }
  if (lane == 0) {
    int gn = cand[b * 32 + i];
    float gl = two_log[b * 32 + i] + one_log[b];
    out[k * BATCH + b]             = (float)gn;
    out[2 * BATCH + k * BATCH + b] = gl;
    p_next[b] = gn;
  }
}

// ---------------- launch ----------------
extern "C" void kernel_launch(void* const* d_in, const int* in_sizes, int n_in,
                              void* d_out, int out_size, void* d_ws, size_t ws_size,
                              hipStream_t stream)
{
  const float* x    = (const float*)d_in[0];
  const float* W1l  = (const float*)d_in[1];
  const float* W1r  = (const float*)d_in[2];
  const float* b1   = (const float*)d_in[3];
  const float* W2l  = (const float*)d_in[4];
  const float* W2r  = (const float*)d_in[5];
  const float* b2   = (const float*)d_in[6];
  const float* disc = (const float*)d_in[7];
  const int*   users= (const int*)d_in[8];
  const int*   pos  = (const int*)d_in[9];
  const int*   adj  = (const int*)d_in[10];
  const int*   edge = (const int*)d_in[11];
  float* out = (float*)d_out;

  char* w = (char*)d_ws;
  const size_t NEED8 = 42414080;   // 8-sublist layout + KG buffers at end
  const size_t NEED2 = 39710720;   // R7-proven layout (KG buffers alias degbuf)
  float *A, *B;
  char* bb;

  if (ws_size >= NEED8) {
    int* head   = (int*)(w);                    // [0, 3,200,000)
    int* degbuf = (int*)(w + 3200000);          // [3.2M, 3.6M)
    int* next   = (int*)(w + 3604480);          // 12.8 MB
    A = (float*)(w + 16404480);
    B = (float*)(w + 29204480);
    bb = w + 42004480;                          // KG buffers (410 KB)
    hipMemsetAsync(head, 0xFF, 3200000, stream);
    k_fill_gemm<<<FILL_B + GEMM_B, 256, 0, stream>>>(edge, head, next, 8, x, W1l, A);
    k_gather_ll<8><<<N_NODES / 8, 256, 0, stream>>>(head, next, A, B, degbuf);
    k_layer1<<<N_NODES / 8, 256, 0, stream>>>(B, degbuf, x, W1r, b1, A);
    k_gather_ll<8><<<N_NODES / 8, 256, 0, stream>>>(head, next, A, B, nullptr);
    k_layer2<<<2048, 64, 0, stream>>>(A, B, degbuf, W2l, W2r, b2);
  } else if (ws_size >= NEED2) {
    // R7-exact layout: KG buffers alias degbuf (deg last read = k_layer2,
    // KG writes start after k_layer2 — proven safe in R7)
    int* head   = (int*)(w);                    // [0, 800,000)
    bb = w + 800000;
    int* degbuf = (int*)(bb);
    int* next   = (int*)(w + 1310720);
    A = (float*)(w + 14110720);
    B = (float*)(w + 26910720);
    hipMemsetAsync(head, 0xFF, 800000, stream);
    k_fill_gemm<<<FILL_B + GEMM_B, 256, 0, stream>>>(edge, head, next, 2, x, W1l, A);
    k_gather_ll<2><<<N_NODES / 8, 256, 0, stream>>>(head, next, A, B, degbuf);
    k_layer1<<<N_NODES / 8, 256, 0, stream>>>(B, degbuf, x, W1r, b1, A);
    k_gather_ll<2><<<N_NODES / 8, 256, 0, stream>>>(head, next, A, B, nullptr);
    k_layer2<<<2048, 64, 0, stream>>>(A, B, degbuf, W2l, W2r, b2);
  } else {
    // fallback: proven atomic-scatter path (R4)
    int* cnt = (int*)w;
    A = (float*)(w + 409600);
    B = (float*)(w + 13209600);
    bb = w + 26009600;
    hipMemsetAsync(cnt, 0, 400000, stream);
    hipMemsetAsync(B, 0, 12800000, stream);
    k_gemm64x32<<<GEMM_B, 256, 0, stream>>>(x, W1l, A);
    k_scatter<<<N_EDGES / 8, 256, 0, stream>>>(edge, A, B, cnt);
    k_layer1<<<GEMM_B, 256, 0, stream>>>(B, cnt, x, W1r, b1, A);
    hipMemsetAsync(B, 0, 12800000, stream);
    k_scatter<<<N_EDGES / 8, 256, 0, stream>>>(edge, A, B, nullptr);
    k_layer2<<<2048, 64, 0, stream>>>(A, B, cnt, W2l, W2r, b2);
  }

  int*   p_cur       = (int*)(bb);
  int*   one_hop_sel = (int*)(bb + 4096);
  float* one_hop_log = (float*)(bb + 8192);
  int*   cand        = (int*)(bb + 12288);
  float* two_log     = (float*)(bb + 143360);
  int*   pos2        = (int*)(bb + 274432);

  // --- KG walk, K_STEP = 2 (R7-proven dispatch structure) ---
  for (int k = 0; k < 2; ++k) {
    unsigned f0, f1, a1a, a1b, a2a, a2b, c1a, c1b, c2a, c2b;
    threefry2x32(0u, 123u, 0u, (unsigned)(2 * k), &f0, &f1);
    threefry2x32(f0, f1, 0u, 0u, &a1a, &a1b);
    threefry2x32(f0, f1, 0u, 1u, &a2a, &a2b);
    threefry2x32(0u, 123u, 0u, (unsigned)(2 * k + 1), &f0, &f1);
    threefry2x32(f0, f1, 0u, 0u, &c1a, &c1b);
    threefry2x32(f0, f1, 0u, 1u, &c2a, &c2b);

    const int* pvec = (k == 0) ? pos : p_cur;
    k_kg_argmax<<<BATCH, 64, 0, stream>>>(A, B, users, pvec, adj, one_hop_sel, one_hop_log);
    k_kg_topk2<<<2 * BATCH, 64, 0, stream>>>(A, B, users, one_hop_sel, pvec, adj,
                                             a1a, a1b, a2a, a2b, c1a, c1b, c2a, c2b,
                                             cand, two_log, pos2);
    k_kg_prune<<<BATCH, 64, 0, stream>>>(disc, users, cand, two_log, pos2,
                                         one_hop_log, out, k, p_cur);
  }
}